// Round 5
// baseline (450.887 us; speedup 1.0000x reference)
//
#include <hip/hip_runtime.h>
#include <hip/hip_bf16.h>

#define NEG_SLOPE 0.2f

typedef __attribute__((ext_vector_type(8))) _Float16 half8;  // MFMA A/B frag (4 VGPR)
typedef __attribute__((ext_vector_type(2))) _Float16 h2v;    // packed f16 pair
typedef __attribute__((ext_vector_type(4))) float f32x4;     // MFMA C/D frag

__device__ __forceinline__ float toF(float x) { return x; }
__device__ __forceinline__ float toF(__hip_bfloat16 x) { return __bfloat162float(x); }
__device__ __forceinline__ float toF(_Float16 x) { return (float)x; }

__device__ __forceinline__ void stT(float* p, size_t i, float v) { p[i] = v; }
__device__ __forceinline__ void stT(__hip_bfloat16* p, size_t i, float v) {
    p[i] = __float2bfloat16(v);
}
__device__ __forceinline__ void stT(_Float16* p, size_t i, float v) { p[i] = (_Float16)v; }

template <typename T> struct WantFlag;
template <> struct WantFlag<float> { static const int v = 0; };
template <> struct WantFlag<__hip_bfloat16> { static const int v = 1; };

template <typename T> struct IsBF { static constexpr bool v = false; };
template <> struct IsBF<__hip_bfloat16> { static constexpr bool v = true; };

// ---------------------------------------------------------------------------
// Dtype detection: bf16-packed vs f32 via exponent band of low half-word.
// ---------------------------------------------------------------------------
__global__ void k_detect(const unsigned* __restrict__ x, int* __restrict__ flag) {
    unsigned u = x[threadIdx.x];
    int lo_exp = (int)((u >> 7) & 0xFFu);
    int ok = (lo_exp >= 90 && lo_exp <= 141) ? 1 : 0;
    unsigned long long b = __ballot(ok);
    if (threadIdx.x == 0) flag[0] = (__popcll(b) >= 48) ? 1 : 0;
}

// ---------------------------------------------------------------------------
// CSR build
// ---------------------------------------------------------------------------
__global__ void k_hist(const int* __restrict__ dst, int E, int* __restrict__ rowptr) {
    int i = blockIdx.x * blockDim.x + threadIdx.x;
    if (i < E) atomicAdd(&rowptr[dst[i] + 1], 1);
}

// 1024-thread shuffle-based scan: 13 tiles of 4096, 4 barriers/tile.
__global__ __launch_bounds__(1024) void k_scan(int* __restrict__ rowptr, int n) {
    __shared__ int wsum[16];
    __shared__ int carry;
    int t = threadIdx.x, lane = t & 63, w = t >> 6;
    if (t == 0) { carry = 0; rowptr[0] = 0; }
    __syncthreads();
    for (int base = 0; base < n; base += 4096) {
        int idx = base + t * 4;
        int c0 = (idx + 0 < n) ? rowptr[idx + 1] : 0;
        int c1 = (idx + 1 < n) ? rowptr[idx + 2] : 0;
        int c2 = (idx + 2 < n) ? rowptr[idx + 3] : 0;
        int c3 = (idx + 3 < n) ? rowptr[idx + 4] : 0;
        int s1 = c0 + c1, s2 = s1 + c2, s3 = s2 + c3;
        int v = s3;
#pragma unroll
        for (int o = 1; o < 64; o <<= 1) {
            int u = __shfl_up(v, o, 64);
            if (lane >= o) v += u;
        }
        if (lane == 63) wsum[w] = v;
        __syncthreads();
        if (t < 16) {
            int x = wsum[t];
#pragma unroll
            for (int o = 1; o < 16; o <<= 1) {
                int u = __shfl_up(x, o, 16);
                if (t >= o) x += u;
            }
            wsum[t] = x;
        }
        __syncthreads();
        int run = carry;
        int off = run + ((w > 0) ? wsum[w - 1] : 0) + (v - s3);
        if (idx + 0 < n) rowptr[idx + 1] = off + c0;
        if (idx + 1 < n) rowptr[idx + 2] = off + s1;
        if (idx + 2 < n) rowptr[idx + 3] = off + s2;
        if (idx + 3 < n) rowptr[idx + 4] = off + s3;
        __syncthreads();
        if (t == 0) carry = run + wsum[15];
        __syncthreads();
    }
}

__global__ void k_scatter(const int* __restrict__ src, const int* __restrict__ dst, int E,
                          const int* __restrict__ rowptr, int* __restrict__ fill,
                          int* __restrict__ csr_src) {
    int i = blockIdx.x * blockDim.x + threadIdx.x;
    if (i < E) {
        int d = dst[i];
        int pos = rowptr[d] + atomicAdd(&fill[d], 1);
        csr_src[pos] = src[i];
    }
}

// ---------------------------------------------------------------------------
// Weight pre-pack for MFMA B-operand, f16, ks-major chunks for LDS staging.
// bid = ks*24 + o*8 + ct; slot holds element (lane,i) =
//   W_o[ks*32 + (lane>>4)*8 + i][ct*16 + (lane&15)]  as _Float16.
// One ks-chunk = 24 slots x 1KB = 24KB, contiguous.
// ---------------------------------------------------------------------------
template <typename WT>
__global__ void k_packW(const int* __restrict__ flag, const WT* __restrict__ W0,
                        const WT* __restrict__ W1, const WT* __restrict__ W2,
                        const WT* __restrict__ b2, int K,
                        _Float16* __restrict__ Bp, float* __restrict__ biasf) {
    if (flag[0] != WantFlag<WT>::v) return;
    int lane = threadIdx.x;  // 64
    int ksteps = K >> 5;
    int nb = 3 * ksteps * 8;
    int bid = blockIdx.x;
    if (bid == nb) {
        biasf[lane * 2 + 0] = toF(b2[lane * 2 + 0]);
        biasf[lane * 2 + 1] = toF(b2[lane * 2 + 1]);
        return;
    }
    int ks = bid / 24;
    int rem = bid - ks * 24;
    int o = rem >> 3, ct = rem & 7;
    const WT* W = (o == 0) ? W0 : ((o == 1) ? W1 : W2);
    int c = ct * 16 + (lane & 15);
    int k0 = ks * 32 + (lane >> 4) * 8;
    _Float16* out = Bp + (size_t)bid * 512 + lane * 8;
#pragma unroll
    for (int i = 0; i < 8; ++i) out[i] = (_Float16)toF(W[(size_t)(k0 + i) * 128 + c]);
}

// ---------------------------------------------------------------------------
// Fused 3-way MFMA GEMM.  O0=A@W0, O1=A@W1, O2=relu(A)@W2+b2.
// Pipeline (R4 post-mortem: keep A-preload, revert to 2-buffer LDS):
// (1) ALL A-fragments preloaded to registers at wave start (KSTEPS template
//     -> static indexing); one-time HBM latency, none per-phase.
// (2) B staged through 2-buffer LDS (48KB -> 3 blocks/CU) via
//     global_load_lds, stage depth 1, counted vmcnt(6) (B is L2-resident,
//     ~300cyc < one compute phase). Drained only at the last step.
// fp32 A split into f16 hi+lo (2 MFMAs, ~22-bit input precision); bf16 A
// converted to f16 (exact); f16 A direct.
// ---------------------------------------------------------------------------
template <typename AT, int FLAGV, int KSTEPS, typename O2T>
__global__ __launch_bounds__(256) void gemm3_mfma(const int* __restrict__ flag,
                                                  const AT* __restrict__ A, int N,
                                                  const _Float16* __restrict__ Bp,
                                                  const float* __restrict__ biasf,
                                                  _Float16* __restrict__ O0,
                                                  _Float16* __restrict__ O1,
                                                  O2T* __restrict__ O2) {
    if (flag[0] != FLAGV) return;  // uniform: no barrier reached if wrong dtype
    __shared__ _Float16 sB[2][12288];  // 2 x 24KB
    const int H = 128;
    const int K = KSTEPS * 32;
    int tid = threadIdx.x;
    int wave = tid >> 6, lane = tid & 63;
    int row0 = (blockIdx.x * 4 + wave) * 16;
    int rr = lane & 15, kg = lane >> 4;
    int arow = min(row0 + rr, N - 1);  // OOB waves still stage + barrier

    f32x4 acc[3][8];
#pragma unroll
    for (int o = 0; o < 3; ++o)
#pragma unroll
        for (int ct = 0; ct < 8; ++ct) acc[o][ct] = f32x4{0.f, 0.f, 0.f, 0.f};

    auto stage = [&](int b, int ksv) {
        const char* gsrc = (const char*)(Bp + (size_t)ksv * 12288) + wave * 1024 + lane * 16;
        char* lbase = (char*)(&sB[b][0]) + wave * 1024;
#pragma unroll
        for (int r = 0; r < 6; ++r) {
            __builtin_amdgcn_global_load_lds(
                (const __attribute__((address_space(1))) unsigned*)(gsrc + r * 4096),
                (__attribute__((address_space(3))) unsigned*)(lbase + r * 4096), 16, 0, 0);
        }
    };

    // ---- preload ALL A fragments (static reg array; removes A latency from loop)
    constexpr int NR = (sizeof(AT) == 4) ? 2 : 1;
    uint4 rA[KSTEPS][NR];
#pragma unroll
    for (int ks = 0; ks < KSTEPS; ++ks) {
        const char* p = (const char*)A + ((size_t)arow * K + ks * 32 + kg * 8) * sizeof(AT);
        rA[ks][0] = *(const uint4*)p;
        if constexpr (NR == 2) rA[ks][1] = *(const uint4*)(p + 16);
    }

    auto compute = [&](const uint4* raw, const _Float16* sb) {
        half8 a0, a1, r0f, r1f;
        if constexpr (sizeof(AT) == 4) {
            union { uint4 u[2]; float f[8]; } cv;
            cv.u[0] = raw[0]; cv.u[1] = raw[1];
#pragma unroll
            for (int i = 0; i < 8; ++i) {
                float a = cv.f[i];
                _Float16 h = (_Float16)a;
                float lof = a - (float)h;
                _Float16 lo = (_Float16)lof;
                bool pos = a > 0.f;
                a0[i] = h; a1[i] = lo;
                r0f[i] = pos ? h : (_Float16)0.f;
                r1f[i] = pos ? lo : (_Float16)0.f;
            }
        } else if constexpr (IsBF<AT>::v) {
            union { uint4 u4; unsigned u[4]; } cv;
            cv.u4 = raw[0];
#pragma unroll
            for (int q = 0; q < 4; ++q) {
                union { unsigned u; float f; } lo, hi;
                lo.u = cv.u[q] << 16;
                hi.u = cv.u[q] & 0xFFFF0000u;
                a0[2 * q] = (_Float16)lo.f;
                a0[2 * q + 1] = (_Float16)hi.f;
                r0f[2 * q] = (_Float16)fmaxf(lo.f, 0.f);
                r0f[2 * q + 1] = (_Float16)fmaxf(hi.f, 0.f);
            }
        } else {
            union { uint4 u4; half8 h; } cv;
            cv.u4 = raw[0];
            a0 = cv.h;
#pragma unroll
            for (int i = 0; i < 8; ++i)
                r0f[i] = (a0[i] > (_Float16)0.f) ? a0[i] : (_Float16)0.f;
        }
#pragma unroll
        for (int ct = 0; ct < 8; ++ct) {
            half8 w0 = *(const half8*)(sb + (0 * 8 + ct) * 512 + lane * 8);
            half8 w1 = *(const half8*)(sb + (1 * 8 + ct) * 512 + lane * 8);
            half8 w2 = *(const half8*)(sb + (2 * 8 + ct) * 512 + lane * 8);
            acc[0][ct] = __builtin_amdgcn_mfma_f32_16x16x32_f16(a0, w0, acc[0][ct], 0, 0, 0);
            acc[1][ct] = __builtin_amdgcn_mfma_f32_16x16x32_f16(a0, w1, acc[1][ct], 0, 0, 0);
            acc[2][ct] = __builtin_amdgcn_mfma_f32_16x16x32_f16(r0f, w2, acc[2][ct], 0, 0, 0);
            if constexpr (sizeof(AT) == 4) {
                acc[0][ct] = __builtin_amdgcn_mfma_f32_16x16x32_f16(a1, w0, acc[0][ct], 0, 0, 0);
                acc[1][ct] = __builtin_amdgcn_mfma_f32_16x16x32_f16(a1, w1, acc[1][ct], 0, 0, 0);
                acc[2][ct] = __builtin_amdgcn_mfma_f32_16x16x32_f16(r1f, w2, acc[2][ct], 0, 0, 0);
            }
        }
    };

    // ---- main loop: 2-buffer, stage depth 1 (B is L2-hot), counted vmcnt
    stage(0, 0);
#pragma unroll
    for (int ks = 0; ks < KSTEPS; ++ks) {
        if (ks + 1 < KSTEPS) {
            stage((ks + 1) & 1, ks + 1);
            asm volatile("s_waitcnt vmcnt(6)" ::: "memory");  // batch ks done; ks+1 in flight
        } else {
            asm volatile("s_waitcnt vmcnt(0)" ::: "memory");
        }
        __builtin_amdgcn_s_barrier();
        compute(rA[ks], &sB[ks & 1][0]);
        __builtin_amdgcn_s_barrier();
    }

    // epilogue: C/D frag mapping col = lane&15, row = (lane>>4)*4 + reg
    int rb = row0 + kg * 4;
#pragma unroll
    for (int ct = 0; ct < 8; ++ct) {
        int c = ct * 16 + rr;
        float bv = biasf[c];
#pragma unroll
        for (int j = 0; j < 4; ++j) {
            int row = rb + j;
            if (row < N) {
                size_t o = (size_t)row * H + c;
                O0[o] = (_Float16)acc[0][ct][j];
                O1[o] = (_Float16)acc[1][ct][j];
                stT(O2, o, acc[2][ct][j] + bv);
            }
        }
    }
}

// ---------------------------------------------------------------------------
// GATv2 edge phase, H=128: 16 lanes per dst node (4 nodes/wave, 16/block).
// Each lane owns 8 features (packed f16 via ext_vector h2v, native v_pk_*);
// dot via v_dot2_f32_f16; reduce = 4-stage 16-lane shuffle amortized over
// 2 concurrent edges; packed-f16 accumulate.
// ---------------------------------------------------------------------------
template <typename IOT, typename T>
__global__ __launch_bounds__(256) void gat_edge16(const int* __restrict__ flag,
                                                  const _Float16* __restrict__ xs,
                                                  const _Float16* __restrict__ xd,
                                                  const int* __restrict__ rowptr,
                                                  const int* __restrict__ csr_src,
                                                  IOT* __restrict__ io,
                                                  const T* __restrict__ att,
                                                  const T* __restrict__ gbias,
                                                  int n, int relu_out) {
    if (flag[0] != WantFlag<T>::v) return;
    int tid = threadIdx.x;
    int l = tid & 15;   // feature lane: feats l*8 .. l*8+7
    int g = tid >> 4;   // group (node) in block
    int dst = blockIdx.x * 16 + g;
    if (blockIdx.x * 16 + ((tid >> 6) << 2) >= n) return;  // whole wave OOB
    int dstc = min(dst, n - 1);
    bool act = dst < n;

    union U4H { uint4 u; h2v h[4]; };
    U4H du; du.u = *(const uint4*)(xd + (size_t)dstc * 128 + l * 8);
    h2v ap[4];
#pragma unroll
    for (int c = 0; c < 4; ++c) {
        ap[c][0] = (_Float16)toF(att[l * 8 + 2 * c]);
        ap[c][1] = (_Float16)toF(att[l * 8 + 2 * c + 1]);
    }
    const _Float16 ks = (_Float16)NEG_SLOPE;
    const h2v k02 = {ks, ks};

    int beg = rowptr[dstc];
    int end = act ? rowptr[dstc + 1] : beg;
    float m = -INFINITY, s = 0.f;
    h2v acc[4];
#pragma unroll
    for (int c = 0; c < 4; ++c) acc[c] = h2v{(_Float16)0.f, (_Float16)0.f};

    for (int j = beg; j < end; j += 2) {
        bool has2 = (j + 1 < end);
        int s0 = csr_src[j];
        int s1 = csr_src[has2 ? j + 1 : j];
        U4H v0, v1;
        v0.u = *(const uint4*)(xs + (size_t)s0 * 128 + l * 8);
        v1.u = *(const uint4*)(xs + (size_t)s1 * 128 + l * 8);
        float p0 = 0.f, p1 = 0.f;
#pragma unroll
        for (int c = 0; c < 4; ++c) {
            h2v t0 = v0.h[c] + du.h[c];
            t0 = __builtin_elementwise_max(t0, t0 * k02);  // leaky: max(h, 0.2h)
            p0 = __builtin_amdgcn_fdot2(t0, ap[c], p0, false);
            h2v t1 = v1.h[c] + du.h[c];
            t1 = __builtin_elementwise_max(t1, t1 * k02);
            p1 = __builtin_amdgcn_fdot2(t1, ap[c], p1, false);
        }
#pragma unroll
        for (int o = 1; o < 16; o <<= 1) {
            p0 += __shfl_xor(p0, o, 16);
            p1 += __shfl_xor(p1, o, 16);
        }
        if (!has2) p1 = -INFINITY;
        float pm = fmaxf(p0, p1);
        float nm = fmaxf(m, pm);
        float sc = __expf(m - nm);  // first iter: exp(-inf)=0
        float w0 = __expf(p0 - nm);
        float w1 = __expf(p1 - nm);
        s = s * sc + w0 + w1;
        _Float16 sch = (_Float16)sc, w0h = (_Float16)w0, w1h = (_Float16)w1;
        h2v scp = {sch, sch};
        h2v w0p = {w0h, w0h};
        h2v w1p = {w1h, w1h};
#pragma unroll
        for (int c = 0; c < 4; ++c)
            acc[c] = acc[c] * scp + v0.h[c] * w0p + v1.h[c] * w1p;
        m = nm;
    }

    if (act) {
        float r = 1.f / (s + 1e-16f);
        size_t base = (size_t)dst * 128 + l * 8;
#pragma unroll
        for (int c = 0; c < 4; ++c) {
            int f0 = l * 8 + 2 * c;
            float v0 = (float)acc[c][0] * r + toF(gbias[f0]) + toF(io[base + 2 * c]);
            float v1 = (float)acc[c][1] * r + toF(gbias[f0 + 1]) + toF(io[base + 2 * c + 1]);
            if (relu_out) { v0 = fmaxf(v0, 0.f); v1 = fmaxf(v1, 0.f); }
            stT(io, base + 2 * c, v0);
            stT(io, base + 2 * c + 1, v1);
        }
    }
}

// ---------------------------------------------------------------------------
// Final layer small GEMMs (128 -> 2): one wave per node.
// ---------------------------------------------------------------------------
template <typename T>
__global__ __launch_bounds__(256) void final_gemm(const int* __restrict__ flag,
                                                  const T* __restrict__ emb,
                                                  const T* __restrict__ Wl,
                                                  const T* __restrict__ Wr,
                                                  const T* __restrict__ Wres,
                                                  const T* __restrict__ bres,
                                                  float* __restrict__ xsf, float* __restrict__ xdf,
                                                  float* __restrict__ resf, int n) {
    if (flag[0] != WantFlag<T>::v) return;
    int wave = threadIdx.x >> 6, lane = threadIdx.x & 63;
    int node = blockIdx.x * 4 + wave;
    if (node >= n) return;
    float e0 = toF(emb[(size_t)node * 128 + lane * 2]);
    float e1 = toF(emb[(size_t)node * 128 + lane * 2 + 1]);
    float r0 = fmaxf(e0, 0.f), r1 = fmaxf(e1, 0.f);
    int k4 = lane * 4;
    float v[6];
    v[0] = e0 * toF(Wl[k4 + 0]) + e1 * toF(Wl[k4 + 2]);
    v[1] = e0 * toF(Wl[k4 + 1]) + e1 * toF(Wl[k4 + 3]);
    v[2] = e0 * toF(Wr[k4 + 0]) + e1 * toF(Wr[k4 + 2]);
    v[3] = e0 * toF(Wr[k4 + 1]) + e1 * toF(Wr[k4 + 3]);
    v[4] = r0 * toF(Wres[k4 + 0]) + r1 * toF(Wres[k4 + 2]);
    v[5] = r0 * toF(Wres[k4 + 1]) + r1 * toF(Wres[k4 + 3]);
#pragma unroll
    for (int i = 0; i < 6; ++i) {
#pragma unroll
        for (int o = 1; o < 64; o <<= 1) v[i] += __shfl_xor(v[i], o, 64);
    }
    if (lane == 0) {
        xsf[node * 2 + 0] = v[0];
        xsf[node * 2 + 1] = v[1];
        xdf[node * 2 + 0] = v[2];
        xdf[node * 2 + 1] = v[3];
        resf[node * 2 + 0] = v[4] + toF(bres[0]);
        resf[node * 2 + 1] = v[5] + toF(bres[1]);
    }
}

// Final edge phase (OUT=2): one thread per dst node.
template <typename T>
__global__ void final_edge(const int* __restrict__ flag, const float* __restrict__ xsf,
                           const float* __restrict__ xdf, const float* __restrict__ resf,
                           const int* __restrict__ rowptr, const int* __restrict__ csr_src,
                           const T* __restrict__ att, const T* __restrict__ gb,
                           T* __restrict__ out, int n) {
    if (flag[0] != WantFlag<T>::v) return;
    int dst = blockIdx.x * blockDim.x + threadIdx.x;
    if (dst >= n) return;
    float2 dv = ((const float2*)xdf)[dst];
    float a0 = toF(att[0]), a1 = toF(att[1]);
    float m = -INFINITY, s = 0.f, acc0 = 0.f, acc1 = 0.f;
    int beg = rowptr[dst], end = rowptr[dst + 1];
    for (int j = beg; j < end; ++j) {
        int src = csr_src[j];
        float2 sv = ((const float2*)xsf)[src];
        float h0 = sv.x + dv.x; h0 = fmaxf(h0, NEG_SLOPE * h0);
        float h1 = sv.y + dv.y; h1 = fmaxf(h1, NEG_SLOPE * h1);
        float e = h0 * a0 + h1 * a1;
        float nm = fmaxf(m, e);
        float sc = __expf(m - nm);
        float w = __expf(e - nm);
        s = s * sc + w;
        acc0 = acc0 * sc + w * sv.x;
        acc1 = acc1 * sc + w * sv.y;
        m = nm;
    }
    float r = 1.f / (s + 1e-16f);
    float2 rv = ((const float2*)resf)[dst];
    stT(out, (size_t)dst * 2 + 0, acc0 * r + toF(gb[0]) + rv.x);
    stT(out, (size_t)dst * 2 + 1, acc1 * r + toF(gb[1]) + rv.y);
}

// ---------------------------------------------------------------------------
extern "C" void kernel_launch(void* const* d_in, const int* in_sizes, int n_in,
                              void* d_out, int out_size, void* d_ws, size_t ws_size,
                              hipStream_t stream) {
    typedef __hip_bfloat16 bf;
    typedef _Float16 f16;
    const int IN = 256, H = 128;
    const int N = in_sizes[0] / IN;  // 50000
    const int E = in_sizes[1] / 2;   // 800000

    const int* ei = (const int*)d_in[1];

    size_t off = 0;
    auto alloc = [&](size_t bytes) {
        void* p = (char*)d_ws + off;
        off += (bytes + 255) & ~(size_t)255;
        return p;
    };
    f16* xs = (f16*)alloc((size_t)N * H * 2);
    f16* xd = (f16*)alloc((size_t)N * H * 2);
    f16* hb = (f16*)alloc((size_t)N * H * 2);
    int* flag = (int*)alloc(256);
    int* rowptr = (int*)alloc((size_t)(N + 1) * 4);
    int* fill = (int*)alloc((size_t)N * 4);
    int* csr_src = (int*)alloc((size_t)E * 4);
    float* xsf = (float*)alloc((size_t)N * 2 * 4);
    float* xdf = (float*)alloc((size_t)N * 2 * 4);
    float* resf = (float*)alloc((size_t)N * 2 * 4);
    f16* Bp0 = (f16*)alloc((size_t)3 * 8 * 8 * 512 * 2);  // 192 KB, ks-major
    f16* Bp1 = (f16*)alloc((size_t)3 * 4 * 8 * 512 * 2);  // 96 KB
    float* bias0 = (float*)alloc(128 * 4);
    float* bias1 = (float*)alloc(128 * 4);

    const int* e_src = ei;
    const int* e_dst = ei + E;

    // ---- dtype detect + CSR build ----
    k_detect<<<1, 64, 0, stream>>>((const unsigned*)d_in[0], flag);
    hipMemsetAsync(rowptr, 0, (size_t)(N + 1) * 4, stream);
    hipMemsetAsync(fill, 0, (size_t)N * 4, stream);
    k_hist<<<(E + 255) / 256, 256, 0, stream>>>(e_dst, E, rowptr);
    k_scan<<<1, 1024, 0, stream>>>(rowptr, N);
    k_scatter<<<(E + 255) / 256, 256, 0, stream>>>(e_src, e_dst, E, rowptr, fill, csr_src);

    // ---- weight pre-pack (dual-dtype dispatch; tiny) ----
    k_packW<float><<<3 * 8 * 8 + 1, 64, 0, stream>>>(flag, (const float*)d_in[2],
                                                     (const float*)d_in[3], (const float*)d_in[14],
                                                     (const float*)d_in[15], IN, Bp0, bias0);
    k_packW<bf><<<3 * 8 * 8 + 1, 64, 0, stream>>>(flag, (const bf*)d_in[2], (const bf*)d_in[3],
                                                  (const bf*)d_in[14], (const bf*)d_in[15], IN,
                                                  Bp0, bias0);
    k_packW<float><<<3 * 4 * 8 + 1, 64, 0, stream>>>(flag, (const float*)d_in[6],
                                                     (const float*)d_in[7], (const float*)d_in[16],
                                                     (const float*)d_in[17], H, Bp1, bias1);
    k_packW<bf><<<3 * 4 * 8 + 1, 64, 0, stream>>>(flag, (const bf*)d_in[6], (const bf*)d_in[7],
                                                  (const bf*)d_in[16], (const bf*)d_in[17], H,
                                                  Bp1, bias1);

    const int g64 = (N + 63) / 64;    // MFMA gemm grid: 64 rows/block
    const int eblk16 = (N + 15) / 16; // gat grid: 16 nodes/block
    const int eblk = (N + 3) / 4;

    // ---- layer 0: x[N,256] -> xs/xd/hb (f16 internals) ----
    gemm3_mfma<float, 0, 8, f16><<<g64, 256, 0, stream>>>(flag, (const float*)d_in[0], N, Bp0,
                                                          bias0, xs, xd, hb);
    gemm3_mfma<bf, 1, 8, f16><<<g64, 256, 0, stream>>>(flag, (const bf*)d_in[0], N, Bp0, bias0,
                                                       xs, xd, hb);
    gat_edge16<f16, float><<<eblk16, 256, 0, stream>>>(flag, xs, xd, rowptr, csr_src, hb,
                                                       (const float*)d_in[4],
                                                       (const float*)d_in[5], N, 1);
    gat_edge16<f16, bf><<<eblk16, 256, 0, stream>>>(flag, xs, xd, rowptr, csr_src, hb,
                                                    (const bf*)d_in[4], (const bf*)d_in[5], N, 1);

    // ---- layer 1: hb[N,128] -> emb resident in d_out's emb region ----
    float* embF = (float*)d_out + (size_t)N * 2;
    bf* embB = (bf*)d_out + (size_t)N * 2;
    gemm3_mfma<f16, 0, 4, float><<<g64, 256, 0, stream>>>(flag, hb, N, Bp1, bias1, xs, xd, embF);
    gemm3_mfma<f16, 1, 4, bf><<<g64, 256, 0, stream>>>(flag, hb, N, Bp1, bias1, xs, xd, embB);
    gat_edge16<float, float><<<eblk16, 256, 0, stream>>>(flag, xs, xd, rowptr, csr_src, embF,
                                                         (const float*)d_in[8],
                                                         (const float*)d_in[9], N, 0);
    gat_edge16<bf, bf><<<eblk16, 256, 0, stream>>>(flag, xs, xd, rowptr, csr_src, embB,
                                                   (const bf*)d_in[8], (const bf*)d_in[9], N, 0);

    // ---- final layer: emb -> out [N,2] ----
    final_gemm<float><<<eblk, 256, 0, stream>>>(flag, embF, (const float*)d_in[10],
                                                (const float*)d_in[11], (const float*)d_in[18],
                                                (const float*)d_in[19], xsf, xdf, resf, N);
    final_gemm<bf><<<eblk, 256, 0, stream>>>(flag, embB, (const bf*)d_in[10],
                                             (const bf*)d_in[11], (const bf*)d_in[18],
                                             (const bf*)d_in[19], xsf, xdf, resf, N);
    final_edge<float><<<(N + 255) / 256, 256, 0, stream>>>(
        flag, xsf, xdf, resf, rowptr, csr_src, (const float*)d_in[12], (const float*)d_in[13],
        (float*)d_out, N);
    final_edge<bf><<<(N + 255) / 256, 256, 0, stream>>>(
        flag, xsf, xdf, resf, rowptr, csr_src, (const bf*)d_in[12], (const bf*)d_in[13],
        (bf*)d_out, N);
}

// Round 6
// 400.412 us; speedup vs baseline: 1.1261x; 1.1261x over previous
//
#include <hip/hip_runtime.h>
#include <hip/hip_bf16.h>

#define NEG_SLOPE 0.2f

typedef __attribute__((ext_vector_type(8))) _Float16 half8;  // MFMA A/B frag (4 VGPR)
typedef __attribute__((ext_vector_type(2))) _Float16 h2v;    // packed f16 pair
typedef __attribute__((ext_vector_type(4))) float f32x4;     // MFMA C/D frag

__device__ __forceinline__ float toF(float x) { return x; }
__device__ __forceinline__ float toF(__hip_bfloat16 x) { return __bfloat162float(x); }
__device__ __forceinline__ float toF(_Float16 x) { return (float)x; }

__device__ __forceinline__ void stT(float* p, size_t i, float v) { p[i] = v; }
__device__ __forceinline__ void stT(__hip_bfloat16* p, size_t i, float v) {
    p[i] = __float2bfloat16(v);
}
__device__ __forceinline__ void stT(_Float16* p, size_t i, float v) { p[i] = (_Float16)v; }

template <typename T> struct WantFlag;
template <> struct WantFlag<float> { static const int v = 0; };
template <> struct WantFlag<__hip_bfloat16> { static const int v = 1; };

template <typename T> struct IsBF { static constexpr bool v = false; };
template <> struct IsBF<__hip_bfloat16> { static constexpr bool v = true; };

// ---------------------------------------------------------------------------
// Dtype detection: bf16-packed vs f32 via exponent band of low half-word.
// ---------------------------------------------------------------------------
__global__ void k_detect(const unsigned* __restrict__ x, int* __restrict__ flag) {
    unsigned u = x[threadIdx.x];
    int lo_exp = (int)((u >> 7) & 0xFFu);
    int ok = (lo_exp >= 90 && lo_exp <= 141) ? 1 : 0;
    unsigned long long b = __ballot(ok);
    if (threadIdx.x == 0) flag[0] = (__popcll(b) >= 48) ? 1 : 0;
}

// ---------------------------------------------------------------------------
// CSR build
// ---------------------------------------------------------------------------
__global__ void k_hist(const int* __restrict__ dst, int E, int* __restrict__ rowptr) {
    int i = blockIdx.x * blockDim.x + threadIdx.x;
    if (i < E) atomicAdd(&rowptr[dst[i] + 1], 1);
}

// 1024-thread shuffle-based scan: 13 tiles of 4096, 4 barriers/tile.
__global__ __launch_bounds__(1024) void k_scan(int* __restrict__ rowptr, int n) {
    __shared__ int wsum[16];
    __shared__ int carry;
    int t = threadIdx.x, lane = t & 63, w = t >> 6;
    if (t == 0) { carry = 0; rowptr[0] = 0; }
    __syncthreads();
    for (int base = 0; base < n; base += 4096) {
        int idx = base + t * 4;
        int c0 = (idx + 0 < n) ? rowptr[idx + 1] : 0;
        int c1 = (idx + 1 < n) ? rowptr[idx + 2] : 0;
        int c2 = (idx + 2 < n) ? rowptr[idx + 3] : 0;
        int c3 = (idx + 3 < n) ? rowptr[idx + 4] : 0;
        int s1 = c0 + c1, s2 = s1 + c2, s3 = s2 + c3;
        int v = s3;
#pragma unroll
        for (int o = 1; o < 64; o <<= 1) {
            int u = __shfl_up(v, o, 64);
            if (lane >= o) v += u;
        }
        if (lane == 63) wsum[w] = v;
        __syncthreads();
        if (t < 16) {
            int x = wsum[t];
#pragma unroll
            for (int o = 1; o < 16; o <<= 1) {
                int u = __shfl_up(x, o, 16);
                if (t >= o) x += u;
            }
            wsum[t] = x;
        }
        __syncthreads();
        int run = carry;
        int off = run + ((w > 0) ? wsum[w - 1] : 0) + (v - s3);
        if (idx + 0 < n) rowptr[idx + 1] = off + c0;
        if (idx + 1 < n) rowptr[idx + 2] = off + s1;
        if (idx + 2 < n) rowptr[idx + 3] = off + s2;
        if (idx + 3 < n) rowptr[idx + 4] = off + s3;
        __syncthreads();
        if (t == 0) carry = run + wsum[15];
        __syncthreads();
    }
}

__global__ void k_scatter(const int* __restrict__ src, const int* __restrict__ dst, int E,
                          const int* __restrict__ rowptr, int* __restrict__ fill,
                          int* __restrict__ csr_src) {
    int i = blockIdx.x * blockDim.x + threadIdx.x;
    if (i < E) {
        int d = dst[i];
        int pos = rowptr[d] + atomicAdd(&fill[d], 1);
        csr_src[pos] = src[i];
    }
}

// ---------------------------------------------------------------------------
// Weight pre-pack for MFMA B-operand, f16, ks-major chunks for LDS staging.
// bid = ks*24 + o*8 + ct; slot holds element (lane,i) =
//   W_o[ks*32 + (lane>>4)*8 + i][ct*16 + (lane&15)]  as _Float16.
// One ks-chunk = 24 slots x 1KB = 24KB, contiguous.
// ---------------------------------------------------------------------------
template <typename WT>
__global__ void k_packW(const int* __restrict__ flag, const WT* __restrict__ W0,
                        const WT* __restrict__ W1, const WT* __restrict__ W2,
                        const WT* __restrict__ b2, int K,
                        _Float16* __restrict__ Bp, float* __restrict__ biasf) {
    if (flag[0] != WantFlag<WT>::v) return;
    int lane = threadIdx.x;  // 64
    int ksteps = K >> 5;
    int nb = 3 * ksteps * 8;
    int bid = blockIdx.x;
    if (bid == nb) {
        biasf[lane * 2 + 0] = toF(b2[lane * 2 + 0]);
        biasf[lane * 2 + 1] = toF(b2[lane * 2 + 1]);
        return;
    }
    int ks = bid / 24;
    int rem = bid - ks * 24;
    int o = rem >> 3, ct = rem & 7;
    const WT* W = (o == 0) ? W0 : ((o == 1) ? W1 : W2);
    int c = ct * 16 + (lane & 15);
    int k0 = ks * 32 + (lane >> 4) * 8;
    _Float16* out = Bp + (size_t)bid * 512 + lane * 8;
#pragma unroll
    for (int i = 0; i < 8; ++i) out[i] = (_Float16)toF(W[(size_t)(k0 + i) * 128 + c]);
}

// ---------------------------------------------------------------------------
// Fused 3-way MFMA GEMM — R3-exact pipeline (46us / 108 VGPR / 14% occ):
// A loaded ONE phase ahead into two named reg buffers (keeps VGPR < 128 —
// the R4 full-preload pushed 136 VGPR -> occupancy halved at the 128 cliff);
// B double-buffered in 48KB LDS via global_load_lds with counted vmcnt
// (8 for fp32 A, 7 for 16-bit A = newest batch in flight), drained only at
// the last step.  O0=A@W0, O1=A@W1, O2=relu(A)@W2+b2.  fp32 A split into
// f16 hi+lo (2 MFMAs, ~22-bit input precision); bf16 A -> f16 exact.
// ---------------------------------------------------------------------------
template <typename AT, int FLAGV, typename O2T>
__global__ __launch_bounds__(256) void gemm3_mfma(const int* __restrict__ flag,
                                                  const AT* __restrict__ A, int N, int K,
                                                  const _Float16* __restrict__ Bp,
                                                  const float* __restrict__ biasf,
                                                  _Float16* __restrict__ O0,
                                                  _Float16* __restrict__ O1,
                                                  O2T* __restrict__ O2) {
    if (flag[0] != FLAGV) return;  // uniform: no barrier reached if wrong dtype
    __shared__ _Float16 sB[2][12288];  // 2 x 24KB
    const int H = 128;
    int tid = threadIdx.x;
    int wave = tid >> 6, lane = tid & 63;
    int row0 = (blockIdx.x * 4 + wave) * 16;
    int rr = lane & 15, kg = lane >> 4;
    int arow = min(row0 + rr, N - 1);  // OOB waves still stage + barrier
    const int ksteps = K >> 5;         // always even (8 or 4)

    f32x4 acc[3][8];
#pragma unroll
    for (int o = 0; o < 3; ++o)
#pragma unroll
        for (int ct = 0; ct < 8; ++ct) acc[o][ct] = f32x4{0.f, 0.f, 0.f, 0.f};

    auto stage = [&](int b, int ksv) {
        const char* gsrc = (const char*)(Bp + (size_t)ksv * 12288) + wave * 1024 + lane * 16;
        char* lbase = (char*)(&sB[b][0]) + wave * 1024;
#pragma unroll
        for (int r = 0; r < 6; ++r) {
            __builtin_amdgcn_global_load_lds(
                (const __attribute__((address_space(1))) unsigned*)(gsrc + r * 4096),
                (__attribute__((address_space(3))) unsigned*)(lbase + r * 4096), 16, 0, 0);
        }
    };
    auto loadA = [&](int ksv, uint4* dst) {
        const char* p = (const char*)A + ((size_t)arow * K + ksv * 32 + kg * 8) * sizeof(AT);
        dst[0] = *(const uint4*)p;
        if constexpr (sizeof(AT) == 4) dst[1] = *(const uint4*)(p + 16);
    };
    auto waitp = [&]() {  // keep newest batch (nA + 6 stage) in flight
        if constexpr (sizeof(AT) == 4)
            asm volatile("s_waitcnt vmcnt(8)" ::: "memory");
        else
            asm volatile("s_waitcnt vmcnt(7)" ::: "memory");
    };
    auto compute = [&](const uint4* raw, const _Float16* sb) {
        half8 a0, a1, r0f, r1f;
        if constexpr (sizeof(AT) == 4) {
            union { uint4 u[2]; float f[8]; } cv;
            cv.u[0] = raw[0]; cv.u[1] = raw[1];
#pragma unroll
            for (int i = 0; i < 8; ++i) {
                float a = cv.f[i];
                _Float16 h = (_Float16)a;
                float lof = a - (float)h;
                _Float16 lo = (_Float16)lof;
                bool pos = a > 0.f;
                a0[i] = h; a1[i] = lo;
                r0f[i] = pos ? h : (_Float16)0.f;
                r1f[i] = pos ? lo : (_Float16)0.f;
            }
        } else if constexpr (IsBF<AT>::v) {
            union { uint4 u4; unsigned u[4]; } cv;
            cv.u4 = raw[0];
#pragma unroll
            for (int q = 0; q < 4; ++q) {
                union { unsigned u; float f; } lo, hi;
                lo.u = cv.u[q] << 16;
                hi.u = cv.u[q] & 0xFFFF0000u;
                a0[2 * q] = (_Float16)lo.f;
                a0[2 * q + 1] = (_Float16)hi.f;
                r0f[2 * q] = (_Float16)fmaxf(lo.f, 0.f);
                r0f[2 * q + 1] = (_Float16)fmaxf(hi.f, 0.f);
            }
        } else {
            union { uint4 u4; half8 h; } cv;
            cv.u4 = raw[0];
            a0 = cv.h;
#pragma unroll
            for (int i = 0; i < 8; ++i)
                r0f[i] = (a0[i] > (_Float16)0.f) ? a0[i] : (_Float16)0.f;
        }
#pragma unroll
        for (int ct = 0; ct < 8; ++ct) {
            half8 w0 = *(const half8*)(sb + (0 * 8 + ct) * 512 + lane * 8);
            half8 w1 = *(const half8*)(sb + (1 * 8 + ct) * 512 + lane * 8);
            half8 w2 = *(const half8*)(sb + (2 * 8 + ct) * 512 + lane * 8);
            acc[0][ct] = __builtin_amdgcn_mfma_f32_16x16x32_f16(a0, w0, acc[0][ct], 0, 0, 0);
            acc[1][ct] = __builtin_amdgcn_mfma_f32_16x16x32_f16(a0, w1, acc[1][ct], 0, 0, 0);
            acc[2][ct] = __builtin_amdgcn_mfma_f32_16x16x32_f16(r0f, w2, acc[2][ct], 0, 0, 0);
            if constexpr (sizeof(AT) == 4) {
                acc[0][ct] = __builtin_amdgcn_mfma_f32_16x16x32_f16(a1, w0, acc[0][ct], 0, 0, 0);
                acc[1][ct] = __builtin_amdgcn_mfma_f32_16x16x32_f16(a1, w1, acc[1][ct], 0, 0, 0);
                acc[2][ct] = __builtin_amdgcn_mfma_f32_16x16x32_f16(r1f, w2, acc[2][ct], 0, 0, 0);
            }
        }
    };

    uint4 rA[2], rB[2];
    loadA(0, rA);
    stage(0, 0);
    for (int ks = 0; ks < ksteps; ks += 2) {
        // phase A: compute ks from buf0/rA; prefetch ks+1 -> buf1/rB
        loadA(ks + 1, rB);
        stage(1, ks + 1);
        waitp();
        __builtin_amdgcn_s_barrier();
        compute(rA, &sB[0][0]);
        __builtin_amdgcn_s_barrier();
        // phase B: compute ks+1 from buf1/rB; prefetch ks+2 -> buf0/rA
        if (ks + 2 < ksteps) {
            loadA(ks + 2, rA);
            stage(0, ks + 2);
            waitp();
        } else {
            asm volatile("s_waitcnt vmcnt(0)" ::: "memory");
        }
        __builtin_amdgcn_s_barrier();
        compute(rB, &sB[1][0]);
        __builtin_amdgcn_s_barrier();
    }

    // epilogue: C/D frag mapping col = lane&15, row = (lane>>4)*4 + reg
    int rb = row0 + kg * 4;
#pragma unroll
    for (int ct = 0; ct < 8; ++ct) {
        int c = ct * 16 + rr;
        float bv = biasf[c];
#pragma unroll
        for (int j = 0; j < 4; ++j) {
            int row = rb + j;
            if (row < N) {
                size_t o = (size_t)row * H + c;
                O0[o] = (_Float16)acc[0][ct][j];
                O1[o] = (_Float16)acc[1][ct][j];
                stT(O2, o, acc[2][ct][j] + bv);
            }
        }
    }
}

// ---------------------------------------------------------------------------
// GATv2 edge phase, H=128: 16 lanes per dst node (4 nodes/wave, 16/block).
// Each lane owns 8 features (packed f16 via ext_vector h2v, native v_pk_*);
// dot via v_dot2_f32_f16; reduce = 4-stage 16-lane shuffle amortized over
// 2 concurrent edges; packed-f16 accumulate.
// FINAL=1 (layer 1): fuse the 128->2 final-layer GEMMs into the epilogue —
// the emb row is already in registers; 8 FMA/lane per dot + 16-lane shuffle
// reduce, write xsf/xdf/resf directly (kills final_gemm dispatch + emb
// re-read; uses unrounded emb -> slightly more accurate).
// ---------------------------------------------------------------------------
template <typename IOT, typename T, int FINAL>
__global__ __launch_bounds__(256) void gat_edge16(const int* __restrict__ flag,
                                                  const _Float16* __restrict__ xs,
                                                  const _Float16* __restrict__ xd,
                                                  const int* __restrict__ rowptr,
                                                  const int* __restrict__ csr_src,
                                                  IOT* __restrict__ io,
                                                  const T* __restrict__ att,
                                                  const T* __restrict__ gbias,
                                                  int n, int relu_out,
                                                  const T* __restrict__ Wl,
                                                  const T* __restrict__ Wr,
                                                  const T* __restrict__ Wres,
                                                  const T* __restrict__ bres,
                                                  float* __restrict__ xsf,
                                                  float* __restrict__ xdf,
                                                  float* __restrict__ resf) {
    if (flag[0] != WantFlag<T>::v) return;
    int tid = threadIdx.x;
    int l = tid & 15;   // feature lane: feats l*8 .. l*8+7
    int g = tid >> 4;   // group (node) in block
    int dst = blockIdx.x * 16 + g;
    if (blockIdx.x * 16 + ((tid >> 6) << 2) >= n) return;  // whole wave OOB
    int dstc = min(dst, n - 1);
    bool act = dst < n;

    union U4H { uint4 u; h2v h[4]; };
    U4H du; du.u = *(const uint4*)(xd + (size_t)dstc * 128 + l * 8);
    h2v ap[4];
#pragma unroll
    for (int c = 0; c < 4; ++c) {
        ap[c][0] = (_Float16)toF(att[l * 8 + 2 * c]);
        ap[c][1] = (_Float16)toF(att[l * 8 + 2 * c + 1]);
    }
    const _Float16 ks = (_Float16)NEG_SLOPE;
    const h2v k02 = {ks, ks};

    int beg = rowptr[dstc];
    int end = act ? rowptr[dstc + 1] : beg;
    float m = -INFINITY, s = 0.f;
    h2v acc[4];
#pragma unroll
    for (int c = 0; c < 4; ++c) acc[c] = h2v{(_Float16)0.f, (_Float16)0.f};

    for (int j = beg; j < end; j += 2) {
        bool has2 = (j + 1 < end);
        int s0 = csr_src[j];
        int s1 = csr_src[has2 ? j + 1 : j];
        U4H v0, v1;
        v0.u = *(const uint4*)(xs + (size_t)s0 * 128 + l * 8);
        v1.u = *(const uint4*)(xs + (size_t)s1 * 128 + l * 8);
        float p0 = 0.f, p1 = 0.f;
#pragma unroll
        for (int c = 0; c < 4; ++c) {
            h2v t0 = v0.h[c] + du.h[c];
            t0 = __builtin_elementwise_max(t0, t0 * k02);  // leaky: max(h, 0.2h)
            p0 = __builtin_amdgcn_fdot2(t0, ap[c], p0, false);
            h2v t1 = v1.h[c] + du.h[c];
            t1 = __builtin_elementwise_max(t1, t1 * k02);
            p1 = __builtin_amdgcn_fdot2(t1, ap[c], p1, false);
        }
#pragma unroll
        for (int o = 1; o < 16; o <<= 1) {
            p0 += __shfl_xor(p0, o, 16);
            p1 += __shfl_xor(p1, o, 16);
        }
        if (!has2) p1 = -INFINITY;
        float pm = fmaxf(p0, p1);
        float nm = fmaxf(m, pm);
        float sc = __expf(m - nm);  // first iter: exp(-inf)=0
        float w0 = __expf(p0 - nm);
        float w1 = __expf(p1 - nm);
        s = s * sc + w0 + w1;
        _Float16 sch = (_Float16)sc, w0h = (_Float16)w0, w1h = (_Float16)w1;
        h2v scp = {sch, sch};
        h2v w0p = {w0h, w0h};
        h2v w1p = {w1h, w1h};
#pragma unroll
        for (int c = 0; c < 4; ++c)
            acc[c] = acc[c] * scp + v0.h[c] * w0p + v1.h[c] * w1p;
        m = nm;
    }

    if (act) {
        float r = 1.f / (s + 1e-16f);
        size_t base = (size_t)dst * 128 + l * 8;
        float ev[8];
#pragma unroll
        for (int c = 0; c < 4; ++c) {
            int f0 = l * 8 + 2 * c;
            float v0 = (float)acc[c][0] * r + toF(gbias[f0]) + toF(io[base + 2 * c]);
            float v1 = (float)acc[c][1] * r + toF(gbias[f0 + 1]) + toF(io[base + 2 * c + 1]);
            if (relu_out) { v0 = fmaxf(v0, 0.f); v1 = fmaxf(v1, 0.f); }
            stT(io, base + 2 * c, v0);
            stT(io, base + 2 * c + 1, v1);
            ev[2 * c] = v0;
            ev[2 * c + 1] = v1;
        }
        if constexpr (FINAL) {
            float d[6] = {0.f, 0.f, 0.f, 0.f, 0.f, 0.f};
#pragma unroll
            for (int f = 0; f < 8; ++f) {
                int fg = (l * 8 + f) * 2;
                float e = ev[f];
                float rp = fmaxf(e, 0.f);
                d[0] += e * toF(Wl[fg]);
                d[1] += e * toF(Wl[fg + 1]);
                d[2] += e * toF(Wr[fg]);
                d[3] += e * toF(Wr[fg + 1]);
                d[4] += rp * toF(Wres[fg]);
                d[5] += rp * toF(Wres[fg + 1]);
            }
#pragma unroll
            for (int i = 0; i < 6; ++i) {
#pragma unroll
                for (int o = 1; o < 16; o <<= 1) d[i] += __shfl_xor(d[i], o, 16);
            }
            if (l == 0) {
                xsf[dst * 2 + 0] = d[0];
                xsf[dst * 2 + 1] = d[1];
                xdf[dst * 2 + 0] = d[2];
                xdf[dst * 2 + 1] = d[3];
                resf[dst * 2 + 0] = d[4] + toF(bres[0]);
                resf[dst * 2 + 1] = d[5] + toF(bres[1]);
            }
        }
    }
}

// ---------------------------------------------------------------------------
// Final edge phase (OUT=2): one thread per dst node, 4-way unrolled online
// softmax (4 independent gathers in flight per merge — breaks the serial
// L2-latency chain that dominated the 1-edge/iter version).
// ---------------------------------------------------------------------------
template <typename T>
__global__ void final_edge(const int* __restrict__ flag, const float* __restrict__ xsf,
                           const float* __restrict__ xdf, const float* __restrict__ resf,
                           const int* __restrict__ rowptr, const int* __restrict__ csr_src,
                           const T* __restrict__ att, const T* __restrict__ gb,
                           T* __restrict__ out, int n) {
    if (flag[0] != WantFlag<T>::v) return;
    int dst = blockIdx.x * blockDim.x + threadIdx.x;
    if (dst >= n) return;
    float2 dv = ((const float2*)xdf)[dst];
    float a0 = toF(att[0]), a1 = toF(att[1]);
    float m = -INFINITY, s = 0.f, acc0 = 0.f, acc1 = 0.f;
    int beg = rowptr[dst], end = rowptr[dst + 1];
    for (int j = beg; j < end; j += 4) {
        int rem = end - j;
        int i1 = (rem > 1) ? 1 : 0, i2 = (rem > 2) ? 2 : 0, i3 = (rem > 3) ? 3 : 0;
        int s0 = csr_src[j];
        int s1 = csr_src[j + i1];
        int s2 = csr_src[j + i2];
        int s3 = csr_src[j + i3];
        float2 v0 = ((const float2*)xsf)[s0];
        float2 v1 = ((const float2*)xsf)[s1];
        float2 v2 = ((const float2*)xsf)[s2];
        float2 v3 = ((const float2*)xsf)[s3];
        float h0, h1, e0, e1, e2, e3;
        h0 = v0.x + dv.x; h0 = fmaxf(h0, NEG_SLOPE * h0);
        h1 = v0.y + dv.y; h1 = fmaxf(h1, NEG_SLOPE * h1);
        e0 = h0 * a0 + h1 * a1;
        h0 = v1.x + dv.x; h0 = fmaxf(h0, NEG_SLOPE * h0);
        h1 = v1.y + dv.y; h1 = fmaxf(h1, NEG_SLOPE * h1);
        e1 = h0 * a0 + h1 * a1;
        h0 = v2.x + dv.x; h0 = fmaxf(h0, NEG_SLOPE * h0);
        h1 = v2.y + dv.y; h1 = fmaxf(h1, NEG_SLOPE * h1);
        e2 = h0 * a0 + h1 * a1;
        h0 = v3.x + dv.x; h0 = fmaxf(h0, NEG_SLOPE * h0);
        h1 = v3.y + dv.y; h1 = fmaxf(h1, NEG_SLOPE * h1);
        e3 = h0 * a0 + h1 * a1;
        if (rem < 2) e1 = -INFINITY;
        if (rem < 3) e2 = -INFINITY;
        if (rem < 4) e3 = -INFINITY;
        float pm = fmaxf(fmaxf(e0, e1), fmaxf(e2, e3));
        float nm = fmaxf(m, pm);
        float sc = __expf(m - nm);
        float w0 = __expf(e0 - nm), w1 = __expf(e1 - nm);
        float w2 = __expf(e2 - nm), w3 = __expf(e3 - nm);
        s = s * sc + ((w0 + w1) + (w2 + w3));
        acc0 = acc0 * sc + ((w0 * v0.x + w1 * v1.x) + (w2 * v2.x + w3 * v3.x));
        acc1 = acc1 * sc + ((w0 * v0.y + w1 * v1.y) + (w2 * v2.y + w3 * v3.y));
        m = nm;
    }
    float r = 1.f / (s + 1e-16f);
    float2 rv = ((const float2*)resf)[dst];
    stT(out, (size_t)dst * 2 + 0, acc0 * r + toF(gb[0]) + rv.x);
    stT(out, (size_t)dst * 2 + 1, acc1 * r + toF(gb[1]) + rv.y);
}

// ---------------------------------------------------------------------------
extern "C" void kernel_launch(void* const* d_in, const int* in_sizes, int n_in,
                              void* d_out, int out_size, void* d_ws, size_t ws_size,
                              hipStream_t stream) {
    typedef __hip_bfloat16 bf;
    typedef _Float16 f16;
    const int IN = 256, H = 128;
    const int N = in_sizes[0] / IN;  // 50000
    const int E = in_sizes[1] / 2;   // 800000

    const int* ei = (const int*)d_in[1];

    size_t off = 0;
    auto alloc = [&](size_t bytes) {
        void* p = (char*)d_ws + off;
        off += (bytes + 255) & ~(size_t)255;
        return p;
    };
    f16* xs = (f16*)alloc((size_t)N * H * 2);
    f16* xd = (f16*)alloc((size_t)N * H * 2);
    f16* hb = (f16*)alloc((size_t)N * H * 2);
    int* flag = (int*)alloc(256);
    int* rowptr = (int*)alloc((size_t)(N + 1) * 4);
    int* fill = (int*)alloc((size_t)N * 4);
    int* csr_src = (int*)alloc((size_t)E * 4);
    float* xsf = (float*)alloc((size_t)N * 2 * 4);
    float* xdf = (float*)alloc((size_t)N * 2 * 4);
    float* resf = (float*)alloc((size_t)N * 2 * 4);
    f16* Bp0 = (f16*)alloc((size_t)3 * 8 * 8 * 512 * 2);  // 192 KB, ks-major
    f16* Bp1 = (f16*)alloc((size_t)3 * 4 * 8 * 512 * 2);  // 96 KB
    float* bias0 = (float*)alloc(128 * 4);
    float* bias1 = (float*)alloc(128 * 4);

    const int* e_src = ei;
    const int* e_dst = ei + E;

    // ---- dtype detect + CSR build ----
    k_detect<<<1, 64, 0, stream>>>((const unsigned*)d_in[0], flag);
    hipMemsetAsync(rowptr, 0, (size_t)(N + 1) * 4, stream);
    hipMemsetAsync(fill, 0, (size_t)N * 4, stream);
    k_hist<<<(E + 255) / 256, 256, 0, stream>>>(e_dst, E, rowptr);
    k_scan<<<1, 1024, 0, stream>>>(rowptr, N);
    k_scatter<<<(E + 255) / 256, 256, 0, stream>>>(e_src, e_dst, E, rowptr, fill, csr_src);

    // ---- weight pre-pack (dual-dtype dispatch; tiny) ----
    k_packW<float><<<3 * 8 * 8 + 1, 64, 0, stream>>>(flag, (const float*)d_in[2],
                                                     (const float*)d_in[3], (const float*)d_in[14],
                                                     (const float*)d_in[15], IN, Bp0, bias0);
    k_packW<bf><<<3 * 8 * 8 + 1, 64, 0, stream>>>(flag, (const bf*)d_in[2], (const bf*)d_in[3],
                                                  (const bf*)d_in[14], (const bf*)d_in[15], IN,
                                                  Bp0, bias0);
    k_packW<float><<<3 * 4 * 8 + 1, 64, 0, stream>>>(flag, (const float*)d_in[6],
                                                     (const float*)d_in[7], (const float*)d_in[16],
                                                     (const float*)d_in[17], H, Bp1, bias1);
    k_packW<bf><<<3 * 4 * 8 + 1, 64, 0, stream>>>(flag, (const bf*)d_in[6], (const bf*)d_in[7],
                                                  (const bf*)d_in[16], (const bf*)d_in[17], H,
                                                  Bp1, bias1);

    const int g64 = (N + 63) / 64;    // MFMA gemm grid: 64 rows/block
    const int eblk16 = (N + 15) / 16; // gat grid: 16 nodes/block

    // ---- layer 0: x[N,256] -> xs/xd/hb (f16 internals) ----
    gemm3_mfma<float, 0, f16><<<g64, 256, 0, stream>>>(flag, (const float*)d_in[0], N, IN, Bp0,
                                                       bias0, xs, xd, hb);
    gemm3_mfma<bf, 1, f16><<<g64, 256, 0, stream>>>(flag, (const bf*)d_in[0], N, IN, Bp0, bias0,
                                                    xs, xd, hb);
    gat_edge16<f16, float, 0><<<eblk16, 256, 0, stream>>>(
        flag, xs, xd, rowptr, csr_src, hb, (const float*)d_in[4], (const float*)d_in[5], N, 1,
        nullptr, nullptr, nullptr, nullptr, nullptr, nullptr, nullptr);
    gat_edge16<f16, bf, 0><<<eblk16, 256, 0, stream>>>(
        flag, xs, xd, rowptr, csr_src, hb, (const bf*)d_in[4], (const bf*)d_in[5], N, 1,
        nullptr, nullptr, nullptr, nullptr, nullptr, nullptr, nullptr);

    // ---- layer 1: hb[N,128] -> emb in d_out + fused final-layer GEMMs ----
    float* embF = (float*)d_out + (size_t)N * 2;
    bf* embB = (bf*)d_out + (size_t)N * 2;
    gemm3_mfma<f16, 0, float><<<g64, 256, 0, stream>>>(flag, hb, N, H, Bp1, bias1, xs, xd, embF);
    gemm3_mfma<f16, 1, bf><<<g64, 256, 0, stream>>>(flag, hb, N, H, Bp1, bias1, xs, xd, embB);
    gat_edge16<float, float, 1><<<eblk16, 256, 0, stream>>>(
        flag, xs, xd, rowptr, csr_src, embF, (const float*)d_in[8], (const float*)d_in[9], N, 0,
        (const float*)d_in[10], (const float*)d_in[11], (const float*)d_in[18],
        (const float*)d_in[19], xsf, xdf, resf);
    gat_edge16<bf, bf, 1><<<eblk16, 256, 0, stream>>>(
        flag, xs, xd, rowptr, csr_src, embB, (const bf*)d_in[8], (const bf*)d_in[9], N, 0,
        (const bf*)d_in[10], (const bf*)d_in[11], (const bf*)d_in[18], (const bf*)d_in[19],
        xsf, xdf, resf);

    // ---- final edge phase: xsf/xdf/resf -> out [N,2] ----
    final_edge<float><<<(N + 255) / 256, 256, 0, stream>>>(
        flag, xsf, xdf, resf, rowptr, csr_src, (const float*)d_in[12], (const float*)d_in[13],
        (float*)d_out, N);
    final_edge<bf><<<(N + 255) / 256, 256, 0, stream>>>(
        flag, xsf, xdf, resf, rowptr, csr_src, (const bf*)d_in[12], (const bf*)d_in[13],
        (bf*)d_out, N);
}

// Round 7
// 367.317 us; speedup vs baseline: 1.2275x; 1.0901x over previous
//
#include <hip/hip_runtime.h>
#include <hip/hip_bf16.h>

#define NEG_SLOPE 0.2f

typedef __attribute__((ext_vector_type(8))) _Float16 half8;  // MFMA A/B frag (4 VGPR)
typedef __attribute__((ext_vector_type(2))) _Float16 h2v;    // packed f16 pair
typedef __attribute__((ext_vector_type(4))) float f32x4;     // MFMA C/D frag

__device__ __forceinline__ float toF(float x) { return x; }
__device__ __forceinline__ float toF(__hip_bfloat16 x) { return __bfloat162float(x); }
__device__ __forceinline__ float toF(_Float16 x) { return (float)x; }

__device__ __forceinline__ void stT(float* p, size_t i, float v) { p[i] = v; }
__device__ __forceinline__ void stT(__hip_bfloat16* p, size_t i, float v) {
    p[i] = __float2bfloat16(v);
}
__device__ __forceinline__ void stT(_Float16* p, size_t i, float v) { p[i] = (_Float16)v; }

template <typename T> struct IsBF { static constexpr bool v = false; };
template <> struct IsBF<__hip_bfloat16> { static constexpr bool v = true; };

// ---------------------------------------------------------------------------
// Dtype detection: bf16-packed vs f32 via exponent band of low half-word.
// ---------------------------------------------------------------------------
__global__ void k_detect(const unsigned* __restrict__ x, int* __restrict__ flag) {
    unsigned u = x[threadIdx.x];
    int lo_exp = (int)((u >> 7) & 0xFFu);
    int ok = (lo_exp >= 90 && lo_exp <= 141) ? 1 : 0;
    unsigned long long b = __ballot(ok);
    if (threadIdx.x == 0) flag[0] = (__popcll(b) >= 48) ? 1 : 0;
}

// ---------------------------------------------------------------------------
// CSR build: hist -> 3-phase parallel scan -> scatter
// ---------------------------------------------------------------------------
__global__ void k_hist(const int* __restrict__ dst, int E, int* __restrict__ rowptr) {
    int i = blockIdx.x * blockDim.x + threadIdx.x;
    if (i < E) atomicAdd(&rowptr[dst[i] + 1], 1);
}

// phase 1: per-1024-chunk inclusive scan (49 blocks in parallel) + block sums
__global__ __launch_bounds__(256) void k_scan1(int* __restrict__ rowptr,
                                               int* __restrict__ blksum, int n) {
    __shared__ int wsum[4];
    int t = threadIdx.x, lane = t & 63, w = t >> 6;
    int idx = blockIdx.x * 1024 + t * 4;
    int c0 = (idx + 0 < n) ? rowptr[idx + 1] : 0;
    int c1 = (idx + 1 < n) ? rowptr[idx + 2] : 0;
    int c2 = (idx + 2 < n) ? rowptr[idx + 3] : 0;
    int c3 = (idx + 3 < n) ? rowptr[idx + 4] : 0;
    int s1 = c0 + c1, s2 = s1 + c2, s3 = s2 + c3;
    int v = s3;
#pragma unroll
    for (int o = 1; o < 64; o <<= 1) {
        int u = __shfl_up(v, o, 64);
        if (lane >= o) v += u;
    }
    if (lane == 63) wsum[w] = v;
    __syncthreads();
    int woff = 0;
#pragma unroll
    for (int i = 0; i < 3; ++i)
        if (i < w) woff += wsum[i];
    int excl = woff + v - s3;
    if (idx + 0 < n) rowptr[idx + 1] = excl + c0;
    if (idx + 1 < n) rowptr[idx + 2] = excl + s1;
    if (idx + 2 < n) rowptr[idx + 3] = excl + s2;
    if (idx + 3 < n) rowptr[idx + 4] = excl + s3;
    if (t == 255) blksum[blockIdx.x] = woff + v;
}

// phase 2: scan the block sums (nblk <= 64) with one wave
__global__ void k_scan2(int* __restrict__ blksum, int nblk) {
    int t = threadIdx.x;  // 64
    int v = (t < nblk) ? blksum[t] : 0;
#pragma unroll
    for (int o = 1; o < 64; o <<= 1) {
        int u = __shfl_up(v, o, 64);
        if (t >= o) v += u;
    }
    if (t < nblk) blksum[t] = v;  // inclusive
}

// phase 3: add scanned block offsets
__global__ void k_scan3(int* __restrict__ rowptr, const int* __restrict__ blksum, int n) {
    int idx = blockIdx.x * blockDim.x + threadIdx.x;
    if (idx < n) {
        int b = idx >> 10;
        if (b > 0) rowptr[idx + 1] += blksum[b - 1];
    }
}

__global__ void k_scatter(const int* __restrict__ src, const int* __restrict__ dst, int E,
                          const int* __restrict__ rowptr, int* __restrict__ fill,
                          int* __restrict__ csr_src) {
    int i = blockIdx.x * blockDim.x + threadIdx.x;
    if (i < E) {
        int d = dst[i];
        int pos = rowptr[d] + atomicAdd(&fill[d], 1);
        csr_src[pos] = src[i];
    }
}

// ---------------------------------------------------------------------------
// Weight pre-pack for MFMA B-operand, f16, ks-major chunks for LDS staging.
// bid = ks*24 + o*8 + ct; slot holds element (lane,i) =
//   W_o[ks*32 + (lane>>4)*8 + i][ct*16 + (lane&15)]  as _Float16.
// ---------------------------------------------------------------------------
template <typename WT>
__device__ void packW_body(const WT* W0, const WT* W1, const WT* W2, const WT* b2, int K,
                           _Float16* Bp, float* biasf) {
    int lane = threadIdx.x;  // 64
    int ksteps = K >> 5;
    int nb = 3 * ksteps * 8;
    int bid = blockIdx.x;
    if (bid == nb) {
        biasf[lane * 2 + 0] = toF(b2[lane * 2 + 0]);
        biasf[lane * 2 + 1] = toF(b2[lane * 2 + 1]);
        return;
    }
    int ks = bid / 24;
    int rem = bid - ks * 24;
    int o = rem >> 3, ct = rem & 7;
    const WT* W = (o == 0) ? W0 : ((o == 1) ? W1 : W2);
    int c = ct * 16 + (lane & 15);
    int k0 = ks * 32 + (lane >> 4) * 8;
    _Float16* out = Bp + (size_t)bid * 512 + lane * 8;
#pragma unroll
    for (int i = 0; i < 8; ++i) out[i] = (_Float16)toF(W[(size_t)(k0 + i) * 128 + c]);
}

__global__ void k_packW(const int* __restrict__ flag, const void* W0, const void* W1,
                        const void* W2, const void* b2, int K, _Float16* __restrict__ Bp,
                        float* __restrict__ biasf) {
    if (flag[0] == 0)
        packW_body<float>((const float*)W0, (const float*)W1, (const float*)W2,
                          (const float*)b2, K, Bp, biasf);
    else
        packW_body<__hip_bfloat16>((const __hip_bfloat16*)W0, (const __hip_bfloat16*)W1,
                                   (const __hip_bfloat16*)W2, (const __hip_bfloat16*)b2, K,
                                   Bp, biasf);
}

// ---------------------------------------------------------------------------
// Fused 3-way MFMA GEMM body — R3-exact pipeline (46us / 108 VGPR):
// A loaded ONE phase ahead into two named reg buffers (VGPR < 128 cliff);
// B double-buffered in 48KB LDS via global_load_lds with counted vmcnt.
// O0=A@W0, O1=A@W1, O2=relu(A)@W2+b2.  fp32 A split into f16 hi+lo.
// ---------------------------------------------------------------------------
template <typename AT, typename O2T>
__device__ void gemm_body(const AT* __restrict__ A, int N, int K,
                          const _Float16* __restrict__ Bp, const float* __restrict__ biasf,
                          _Float16* __restrict__ O0, _Float16* __restrict__ O1,
                          O2T* __restrict__ O2, _Float16 (*sB)[12288]) {
    const int H = 128;
    int tid = threadIdx.x;
    int wave = tid >> 6, lane = tid & 63;
    int row0 = (blockIdx.x * 4 + wave) * 16;
    int rr = lane & 15, kg = lane >> 4;
    int arow = min(row0 + rr, N - 1);  // OOB waves still stage + barrier
    const int ksteps = K >> 5;         // always even (8 or 4)

    f32x4 acc[3][8];
#pragma unroll
    for (int o = 0; o < 3; ++o)
#pragma unroll
        for (int ct = 0; ct < 8; ++ct) acc[o][ct] = f32x4{0.f, 0.f, 0.f, 0.f};

    auto stage = [&](int b, int ksv) {
        const char* gsrc = (const char*)(Bp + (size_t)ksv * 12288) + wave * 1024 + lane * 16;
        char* lbase = (char*)(&sB[b][0]) + wave * 1024;
#pragma unroll
        for (int r = 0; r < 6; ++r) {
            __builtin_amdgcn_global_load_lds(
                (const __attribute__((address_space(1))) unsigned*)(gsrc + r * 4096),
                (__attribute__((address_space(3))) unsigned*)(lbase + r * 4096), 16, 0, 0);
        }
    };
    auto loadA = [&](int ksv, uint4* dst) {
        const char* p = (const char*)A + ((size_t)arow * K + ksv * 32 + kg * 8) * sizeof(AT);
        dst[0] = *(const uint4*)p;
        if constexpr (sizeof(AT) == 4) dst[1] = *(const uint4*)(p + 16);
    };
    auto waitp = [&]() {  // keep newest batch (nA + 6 stage) in flight
        if constexpr (sizeof(AT) == 4)
            asm volatile("s_waitcnt vmcnt(8)" ::: "memory");
        else
            asm volatile("s_waitcnt vmcnt(7)" ::: "memory");
    };
    auto compute = [&](const uint4* raw, const _Float16* sb) {
        half8 a0, a1, r0f, r1f;
        if constexpr (sizeof(AT) == 4) {
            union { uint4 u[2]; float f[8]; } cv;
            cv.u[0] = raw[0]; cv.u[1] = raw[1];
#pragma unroll
            for (int i = 0; i < 8; ++i) {
                float a = cv.f[i];
                _Float16 h = (_Float16)a;
                float lof = a - (float)h;
                _Float16 lo = (_Float16)lof;
                bool pos = a > 0.f;
                a0[i] = h; a1[i] = lo;
                r0f[i] = pos ? h : (_Float16)0.f;
                r1f[i] = pos ? lo : (_Float16)0.f;
            }
        } else if constexpr (IsBF<AT>::v) {
            union { uint4 u4; unsigned u[4]; } cv;
            cv.u4 = raw[0];
#pragma unroll
            for (int q = 0; q < 4; ++q) {
                union { unsigned u; float f; } lo, hi;
                lo.u = cv.u[q] << 16;
                hi.u = cv.u[q] & 0xFFFF0000u;
                a0[2 * q] = (_Float16)lo.f;
                a0[2 * q + 1] = (_Float16)hi.f;
                r0f[2 * q] = (_Float16)fmaxf(lo.f, 0.f);
                r0f[2 * q + 1] = (_Float16)fmaxf(hi.f, 0.f);
            }
        } else {
            union { uint4 u4; half8 h; } cv;
            cv.u4 = raw[0];
            a0 = cv.h;
#pragma unroll
            for (int i = 0; i < 8; ++i)
                r0f[i] = (a0[i] > (_Float16)0.f) ? a0[i] : (_Float16)0.f;
        }
#pragma unroll
        for (int ct = 0; ct < 8; ++ct) {
            half8 w0 = *(const half8*)(sb + (0 * 8 + ct) * 512 + lane * 8);
            half8 w1 = *(const half8*)(sb + (1 * 8 + ct) * 512 + lane * 8);
            half8 w2 = *(const half8*)(sb + (2 * 8 + ct) * 512 + lane * 8);
            acc[0][ct] = __builtin_amdgcn_mfma_f32_16x16x32_f16(a0, w0, acc[0][ct], 0, 0, 0);
            acc[1][ct] = __builtin_amdgcn_mfma_f32_16x16x32_f16(a0, w1, acc[1][ct], 0, 0, 0);
            acc[2][ct] = __builtin_amdgcn_mfma_f32_16x16x32_f16(r0f, w2, acc[2][ct], 0, 0, 0);
            if constexpr (sizeof(AT) == 4) {
                acc[0][ct] = __builtin_amdgcn_mfma_f32_16x16x32_f16(a1, w0, acc[0][ct], 0, 0, 0);
                acc[1][ct] = __builtin_amdgcn_mfma_f32_16x16x32_f16(a1, w1, acc[1][ct], 0, 0, 0);
                acc[2][ct] = __builtin_amdgcn_mfma_f32_16x16x32_f16(r1f, w2, acc[2][ct], 0, 0, 0);
            }
        }
    };

    uint4 rA[2], rB[2];
    loadA(0, rA);
    stage(0, 0);
    for (int ks = 0; ks < ksteps; ks += 2) {
        loadA(ks + 1, rB);
        stage(1, ks + 1);
        waitp();
        __builtin_amdgcn_s_barrier();
        compute(rA, &sB[0][0]);
        __builtin_amdgcn_s_barrier();
        if (ks + 2 < ksteps) {
            loadA(ks + 2, rA);
            stage(0, ks + 2);
            waitp();
        } else {
            asm volatile("s_waitcnt vmcnt(0)" ::: "memory");
        }
        __builtin_amdgcn_s_barrier();
        compute(rB, &sB[1][0]);
        __builtin_amdgcn_s_barrier();
    }

    int rb = row0 + kg * 4;
#pragma unroll
    for (int ct = 0; ct < 8; ++ct) {
        int c = ct * 16 + rr;
        float bv = biasf[c];
#pragma unroll
        for (int j = 0; j < 4; ++j) {
            int row = rb + j;
            if (row < N) {
                size_t o = (size_t)row * H + c;
                O0[o] = (_Float16)acc[0][ct][j];
                O1[o] = (_Float16)acc[1][ct][j];
                stT(O2, o, acc[2][ct][j] + bv);
            }
        }
    }
}

// unified gemm kernel: LAYER=0 (A = external dtype, O2 = hb f16),
// LAYER=1 (A = f16 hb, O2 = embF f32 / embB bf16 by flag).
template <int LAYER>
__global__ __launch_bounds__(256) void gemm3_u(const int* __restrict__ flag, const void* Aext,
                                               const _Float16* Af16, int N, int K,
                                               const _Float16* __restrict__ Bp,
                                               const float* __restrict__ biasf,
                                               _Float16* __restrict__ O0,
                                               _Float16* __restrict__ O1, _Float16* O2h,
                                               float* O2f, __hip_bfloat16* O2b) {
    __shared__ _Float16 sB[2][12288];  // 48KB
    int f = flag[0];
    if constexpr (LAYER == 0) {
        if (f == 0)
            gemm_body<float, _Float16>((const float*)Aext, N, K, Bp, biasf, O0, O1, O2h, sB);
        else
            gemm_body<__hip_bfloat16, _Float16>((const __hip_bfloat16*)Aext, N, K, Bp, biasf,
                                                O0, O1, O2h, sB);
    } else {
        if (f == 0)
            gemm_body<_Float16, float>(Af16, N, K, Bp, biasf, O0, O1, O2f, sB);
        else
            gemm_body<_Float16, __hip_bfloat16>(Af16, N, K, Bp, biasf, O0, O1, O2b, sB);
    }
}

// ---------------------------------------------------------------------------
// GATv2 edge phase body, H=128: 16 lanes per dst node, 4 edges/iteration
// (4 gathers in flight; shuffle tree + softmax merge amortized over 4).
// FINAL=1: fuse the 128->2 final-layer GEMMs into the epilogue.
// ---------------------------------------------------------------------------
template <typename IOT, typename T, int FINAL>
__device__ void gat_body(const _Float16* __restrict__ xs, const _Float16* __restrict__ xd,
                         const int* __restrict__ rowptr, const int* __restrict__ csr_src,
                         IOT* __restrict__ io, const T* __restrict__ att,
                         const T* __restrict__ gbias, int n, int relu_out,
                         const T* __restrict__ Wl, const T* __restrict__ Wr,
                         const T* __restrict__ Wres, const T* __restrict__ bres,
                         float* __restrict__ xsf, float* __restrict__ xdf,
                         float* __restrict__ resf) {
    int tid = threadIdx.x;
    int l = tid & 15;   // feature lane: feats l*8 .. l*8+7
    int g = tid >> 4;   // group (node) in block
    int dst = blockIdx.x * 16 + g;
    if (blockIdx.x * 16 + ((tid >> 6) << 2) >= n) return;  // whole wave OOB
    int dstc = min(dst, n - 1);
    bool act = dst < n;

    union U4H { uint4 u; h2v h[4]; };
    U4H du; du.u = *(const uint4*)(xd + (size_t)dstc * 128 + l * 8);
    h2v ap[4];
#pragma unroll
    for (int c = 0; c < 4; ++c) {
        ap[c][0] = (_Float16)toF(att[l * 8 + 2 * c]);
        ap[c][1] = (_Float16)toF(att[l * 8 + 2 * c + 1]);
    }
    const _Float16 ks = (_Float16)NEG_SLOPE;
    const h2v k02 = {ks, ks};

    int beg = rowptr[dstc];
    int end = act ? rowptr[dstc + 1] : beg;
    float m = -INFINITY, s = 0.f;
    h2v acc[4];
#pragma unroll
    for (int c = 0; c < 4; ++c) acc[c] = h2v{(_Float16)0.f, (_Float16)0.f};

    for (int j = beg; j < end; j += 4) {
        int rem = end - j;
        int i1 = (rem > 1) ? 1 : 0, i2 = (rem > 2) ? 2 : 0, i3 = (rem > 3) ? 3 : 0;
        int s0 = csr_src[j];
        int s1 = csr_src[j + i1];
        int s2 = csr_src[j + i2];
        int s3 = csr_src[j + i3];
        U4H v0, v1, v2, v3;
        v0.u = *(const uint4*)(xs + (size_t)s0 * 128 + l * 8);
        v1.u = *(const uint4*)(xs + (size_t)s1 * 128 + l * 8);
        v2.u = *(const uint4*)(xs + (size_t)s2 * 128 + l * 8);
        v3.u = *(const uint4*)(xs + (size_t)s3 * 128 + l * 8);
        float p0 = 0.f, p1 = 0.f, p2 = 0.f, p3 = 0.f;
#pragma unroll
        for (int c = 0; c < 4; ++c) {
            h2v t0 = v0.h[c] + du.h[c];
            t0 = __builtin_elementwise_max(t0, t0 * k02);  // leaky: max(h, 0.2h)
            p0 = __builtin_amdgcn_fdot2(t0, ap[c], p0, false);
            h2v t1 = v1.h[c] + du.h[c];
            t1 = __builtin_elementwise_max(t1, t1 * k02);
            p1 = __builtin_amdgcn_fdot2(t1, ap[c], p1, false);
            h2v t2 = v2.h[c] + du.h[c];
            t2 = __builtin_elementwise_max(t2, t2 * k02);
            p2 = __builtin_amdgcn_fdot2(t2, ap[c], p2, false);
            h2v t3 = v3.h[c] + du.h[c];
            t3 = __builtin_elementwise_max(t3, t3 * k02);
            p3 = __builtin_amdgcn_fdot2(t3, ap[c], p3, false);
        }
#pragma unroll
        for (int o = 1; o < 16; o <<= 1) {
            p0 += __shfl_xor(p0, o, 16);
            p1 += __shfl_xor(p1, o, 16);
            p2 += __shfl_xor(p2, o, 16);
            p3 += __shfl_xor(p3, o, 16);
        }
        if (rem < 2) p1 = -INFINITY;
        if (rem < 3) p2 = -INFINITY;
        if (rem < 4) p3 = -INFINITY;
        float pm = fmaxf(fmaxf(p0, p1), fmaxf(p2, p3));
        float nm = fmaxf(m, pm);
        float sc = __expf(m - nm);  // first iter: exp(-inf)=0
        float w0 = __expf(p0 - nm);
        float w1 = __expf(p1 - nm);
        float w2 = __expf(p2 - nm);
        float w3 = __expf(p3 - nm);
        s = s * sc + ((w0 + w1) + (w2 + w3));
        _Float16 sch = (_Float16)sc;
        _Float16 w0h = (_Float16)w0, w1h = (_Float16)w1;
        _Float16 w2h = (_Float16)w2, w3h = (_Float16)w3;
        h2v scp = {sch, sch};
        h2v w0p = {w0h, w0h}, w1p = {w1h, w1h};
        h2v w2p = {w2h, w2h}, w3p = {w3h, w3h};
#pragma unroll
        for (int c = 0; c < 4; ++c)
            acc[c] = acc[c] * scp +
                     ((v0.h[c] * w0p + v1.h[c] * w1p) + (v2.h[c] * w2p + v3.h[c] * w3p));
        m = nm;
    }

    if (act) {
        float r = 1.f / (s + 1e-16f);
        size_t base = (size_t)dst * 128 + l * 8;
        float ev[8];
#pragma unroll
        for (int c = 0; c < 4; ++c) {
            int f0 = l * 8 + 2 * c;
            float v0 = (float)acc[c][0] * r + toF(gbias[f0]) + toF(io[base + 2 * c]);
            float v1 = (float)acc[c][1] * r + toF(gbias[f0 + 1]) + toF(io[base + 2 * c + 1]);
            if (relu_out) { v0 = fmaxf(v0, 0.f); v1 = fmaxf(v1, 0.f); }
            stT(io, base + 2 * c, v0);
            stT(io, base + 2 * c + 1, v1);
            ev[2 * c] = v0;
            ev[2 * c + 1] = v1;
        }
        if constexpr (FINAL) {
            float d[6] = {0.f, 0.f, 0.f, 0.f, 0.f, 0.f};
#pragma unroll
            for (int f = 0; f < 8; ++f) {
                int fg = (l * 8 + f) * 2;
                float e = ev[f];
                float rp = fmaxf(e, 0.f);
                d[0] += e * toF(Wl[fg]);
                d[1] += e * toF(Wl[fg + 1]);
                d[2] += e * toF(Wr[fg]);
                d[3] += e * toF(Wr[fg + 1]);
                d[4] += rp * toF(Wres[fg]);
                d[5] += rp * toF(Wres[fg + 1]);
            }
#pragma unroll
            for (int i = 0; i < 6; ++i) {
#pragma unroll
                for (int o = 1; o < 16; o <<= 1) d[i] += __shfl_xor(d[i], o, 16);
            }
            if (l == 0) {
                xsf[dst * 2 + 0] = d[0];
                xsf[dst * 2 + 1] = d[1];
                xdf[dst * 2 + 0] = d[2];
                xdf[dst * 2 + 1] = d[3];
                resf[dst * 2 + 0] = d[4] + toF(bres[0]);
                resf[dst * 2 + 1] = d[5] + toF(bres[1]);
            }
        }
    }
}

// unified gat kernel: FINAL=0 (io = hb f16), FINAL=1 (io = embF/embB by flag,
// fused final-layer 128->2 GEMMs).
template <int FINAL>
__global__ __launch_bounds__(256) void gat_u(const int* __restrict__ flag,
                                             const _Float16* __restrict__ xs,
                                             const _Float16* __restrict__ xd,
                                             const int* __restrict__ rowptr,
                                             const int* __restrict__ csr_src, _Float16* io_h,
                                             float* io_f, __hip_bfloat16* io_b, const void* att,
                                             const void* gbias, int n, int relu_out,
                                             const void* Wl, const void* Wr, const void* Wres,
                                             const void* bres, float* xsf, float* xdf,
                                             float* resf) {
    typedef __hip_bfloat16 bf;
    int f = flag[0];
    if constexpr (FINAL == 0) {
        if (f == 0)
            gat_body<_Float16, float, 0>(xs, xd, rowptr, csr_src, io_h, (const float*)att,
                                         (const float*)gbias, n, relu_out, nullptr, nullptr,
                                         nullptr, nullptr, nullptr, nullptr, nullptr);
        else
            gat_body<_Float16, bf, 0>(xs, xd, rowptr, csr_src, io_h, (const bf*)att,
                                      (const bf*)gbias, n, relu_out, nullptr, nullptr, nullptr,
                                      nullptr, nullptr, nullptr, nullptr);
    } else {
        if (f == 0)
            gat_body<float, float, 1>(xs, xd, rowptr, csr_src, io_f, (const float*)att,
                                      (const float*)gbias, n, relu_out, (const float*)Wl,
                                      (const float*)Wr, (const float*)Wres, (const float*)bres,
                                      xsf, xdf, resf);
        else
            gat_body<bf, bf, 1>(xs, xd, rowptr, csr_src, io_b, (const bf*)att, (const bf*)gbias,
                                n, relu_out, (const bf*)Wl, (const bf*)Wr, (const bf*)Wres,
                                (const bf*)bres, xsf, xdf, resf);
    }
}

// ---------------------------------------------------------------------------
// Final edge phase (OUT=2): one thread per dst node, 4-way unrolled online
// softmax.
// ---------------------------------------------------------------------------
template <typename T>
__device__ void fe_body(const float* __restrict__ xsf, const float* __restrict__ xdf,
                        const float* __restrict__ resf, const int* __restrict__ rowptr,
                        const int* __restrict__ csr_src, const T* __restrict__ att,
                        const T* __restrict__ gb, T* __restrict__ out, int n) {
    int dst = blockIdx.x * blockDim.x + threadIdx.x;
    if (dst >= n) return;
    float2 dv = ((const float2*)xdf)[dst];
    float a0 = toF(att[0]), a1 = toF(att[1]);
    float m = -INFINITY, s = 0.f, acc0 = 0.f, acc1 = 0.f;
    int beg = rowptr[dst], end = rowptr[dst + 1];
    for (int j = beg; j < end; j += 4) {
        int rem = end - j;
        int i1 = (rem > 1) ? 1 : 0, i2 = (rem > 2) ? 2 : 0, i3 = (rem > 3) ? 3 : 0;
        int s0 = csr_src[j];
        int s1 = csr_src[j + i1];
        int s2 = csr_src[j + i2];
        int s3 = csr_src[j + i3];
        float2 v0 = ((const float2*)xsf)[s0];
        float2 v1 = ((const float2*)xsf)[s1];
        float2 v2 = ((const float2*)xsf)[s2];
        float2 v3 = ((const float2*)xsf)[s3];
        float h0, h1, e0, e1, e2, e3;
        h0 = v0.x + dv.x; h0 = fmaxf(h0, NEG_SLOPE * h0);
        h1 = v0.y + dv.y; h1 = fmaxf(h1, NEG_SLOPE * h1);
        e0 = h0 * a0 + h1 * a1;
        h0 = v1.x + dv.x; h0 = fmaxf(h0, NEG_SLOPE * h0);
        h1 = v1.y + dv.y; h1 = fmaxf(h1, NEG_SLOPE * h1);
        e1 = h0 * a0 + h1 * a1;
        h0 = v2.x + dv.x; h0 = fmaxf(h0, NEG_SLOPE * h0);
        h1 = v2.y + dv.y; h1 = fmaxf(h1, NEG_SLOPE * h1);
        e2 = h0 * a0 + h1 * a1;
        h0 = v3.x + dv.x; h0 = fmaxf(h0, NEG_SLOPE * h0);
        h1 = v3.y + dv.y; h1 = fmaxf(h1, NEG_SLOPE * h1);
        e3 = h0 * a0 + h1 * a1;
        if (rem < 2) e1 = -INFINITY;
        if (rem < 3) e2 = -INFINITY;
        if (rem < 4) e3 = -INFINITY;
        float pm = fmaxf(fmaxf(e0, e1), fmaxf(e2, e3));
        float nm = fmaxf(m, pm);
        float sc = __expf(m - nm);
        float w0 = __expf(e0 - nm), w1 = __expf(e1 - nm);
        float w2 = __expf(e2 - nm), w3 = __expf(e3 - nm);
        s = s * sc + ((w0 + w1) + (w2 + w3));
        acc0 = acc0 * sc + ((w0 * v0.x + w1 * v1.x) + (w2 * v2.x + w3 * v3.x));
        acc1 = acc1 * sc + ((w0 * v0.y + w1 * v1.y) + (w2 * v2.y + w3 * v3.y));
        m = nm;
    }
    float r = 1.f / (s + 1e-16f);
    float2 rv = ((const float2*)resf)[dst];
    stT(out, (size_t)dst * 2 + 0, acc0 * r + toF(gb[0]) + rv.x);
    stT(out, (size_t)dst * 2 + 1, acc1 * r + toF(gb[1]) + rv.y);
}

__global__ void final_edge_u(const int* __restrict__ flag, const float* __restrict__ xsf,
                             const float* __restrict__ xdf, const float* __restrict__ resf,
                             const int* __restrict__ rowptr, const int* __restrict__ csr_src,
                             const void* att, const void* gb, void* out, int n) {
    typedef __hip_bfloat16 bf;
    if (flag[0] == 0)
        fe_body<float>(xsf, xdf, resf, rowptr, csr_src, (const float*)att, (const float*)gb,
                       (float*)out, n);
    else
        fe_body<bf>(xsf, xdf, resf, rowptr, csr_src, (const bf*)att, (const bf*)gb, (bf*)out, n);
}

// ---------------------------------------------------------------------------
extern "C" void kernel_launch(void* const* d_in, const int* in_sizes, int n_in,
                              void* d_out, int out_size, void* d_ws, size_t ws_size,
                              hipStream_t stream) {
    typedef __hip_bfloat16 bf;
    typedef _Float16 f16;
    const int IN = 256, H = 128;
    const int N = in_sizes[0] / IN;  // 50000
    const int E = in_sizes[1] / 2;   // 800000

    const int* ei = (const int*)d_in[1];

    size_t off = 0;
    auto alloc = [&](size_t bytes) {
        void* p = (char*)d_ws + off;
        off += (bytes + 255) & ~(size_t)255;
        return p;
    };
    f16* xs = (f16*)alloc((size_t)N * H * 2);
    f16* xd = (f16*)alloc((size_t)N * H * 2);
    f16* hb = (f16*)alloc((size_t)N * H * 2);
    int* flag = (int*)alloc(256);
    int* rowptr = (int*)alloc((size_t)(N + 1) * 4);
    int* fill = (int*)alloc((size_t)N * 4);
    int* blksum = (int*)alloc(256 * 4);
    int* csr_src = (int*)alloc((size_t)E * 4);
    float* xsf = (float*)alloc((size_t)N * 2 * 4);
    float* xdf = (float*)alloc((size_t)N * 2 * 4);
    float* resf = (float*)alloc((size_t)N * 2 * 4);
    f16* Bp0 = (f16*)alloc((size_t)3 * 8 * 8 * 512 * 2);  // 192 KB, ks-major
    f16* Bp1 = (f16*)alloc((size_t)3 * 4 * 8 * 512 * 2);  // 96 KB
    float* bias0 = (float*)alloc(128 * 4);
    float* bias1 = (float*)alloc(128 * 4);

    const int* e_src = ei;
    const int* e_dst = ei + E;

    // ---- dtype detect + CSR build ----
    k_detect<<<1, 64, 0, stream>>>((const unsigned*)d_in[0], flag);
    hipMemsetAsync(rowptr, 0, (size_t)(N + 1) * 4, stream);
    hipMemsetAsync(fill, 0, (size_t)N * 4, stream);
    k_hist<<<(E + 255) / 256, 256, 0, stream>>>(e_dst, E, rowptr);
    const int nblk = (N + 1023) / 1024;  // 49 <= 64
    k_scan1<<<nblk, 256, 0, stream>>>(rowptr, blksum, N);
    k_scan2<<<1, 64, 0, stream>>>(blksum, nblk);
    k_scan3<<<(N + 255) / 256, 256, 0, stream>>>(rowptr, blksum, N);
    k_scatter<<<(E + 255) / 256, 256, 0, stream>>>(e_src, e_dst, E, rowptr, fill, csr_src);

    // ---- weight pre-pack (runtime dtype branch; tiny) ----
    k_packW<<<3 * 8 * 8 + 1, 64, 0, stream>>>(flag, d_in[2], d_in[3], d_in[14], d_in[15], IN,
                                              Bp0, bias0);
    k_packW<<<3 * 4 * 8 + 1, 64, 0, stream>>>(flag, d_in[6], d_in[7], d_in[16], d_in[17], H,
                                              Bp1, bias1);

    const int g64 = (N + 63) / 64;     // MFMA gemm grid: 64 rows/block
    const int eblk16 = (N + 15) / 16;  // gat grid: 16 nodes/block

    float* embF = (float*)d_out + (size_t)N * 2;
    bf* embB = (bf*)d_out + (size_t)N * 2;

    // ---- layer 0: x[N,256] -> xs/xd/hb (f16 internals) ----
    gemm3_u<0><<<g64, 256, 0, stream>>>(flag, d_in[0], nullptr, N, IN, Bp0, bias0, xs, xd, hb,
                                        nullptr, nullptr);
    gat_u<0><<<eblk16, 256, 0, stream>>>(flag, xs, xd, rowptr, csr_src, hb, nullptr, nullptr,
                                         d_in[4], d_in[5], N, 1, nullptr, nullptr, nullptr,
                                         nullptr, nullptr, nullptr, nullptr);

    // ---- layer 1: hb[N,128] -> emb in d_out + fused final-layer GEMMs ----
    gemm3_u<1><<<g64, 256, 0, stream>>>(flag, nullptr, hb, N, H, Bp1, bias1, xs, xd, nullptr,
                                        embF, embB);
    gat_u<1><<<eblk16, 256, 0, stream>>>(flag, xs, xd, rowptr, csr_src, nullptr, embF, embB,
                                         d_in[8], d_in[9], N, 0, d_in[10], d_in[11], d_in[18],
                                         d_in[19], xsf, xdf, resf);

    // ---- final edge phase: xsf/xdf/resf -> out [N,2] ----
    final_edge_u<<<(N + 255) / 256, 256, 0, stream>>>(flag, xsf, xdf, resf, rowptr, csr_src,
                                                      d_in[12], d_in[13], d_out, N);
}